// Round 3
// baseline (417.342 us; speedup 1.0000x reference)
//
#include <hip/hip_runtime.h>
#include <hip/hip_bf16.h>

#define NNODES 50000
#define NEDGES 600000
#define NB 196     // ceil(NNODES/256)
#define NBKT 196   // coarse buckets (dst >> 8)
#define SB 192     // edge-pass blocks (hist + count + scatter)
#define SCH (NEDGES / SB)   // 3125 edges per block (exact)

typedef short vs8 __attribute__((ext_vector_type(8)));
typedef float floatx4 __attribute__((ext_vector_type(4)));

__device__ __forceinline__ float us2f(unsigned short u) {
    unsigned int x = ((unsigned int)u) << 16;
    float f;
    __builtin_memcpy(&f, &x, 4);
    return f;
}
__device__ __forceinline__ unsigned short f2us(float f) {
    unsigned int x;
    __builtin_memcpy(&x, &f, 4);
    unsigned int r = x + 0x7fffu + ((x >> 16) & 1u);  // RNE
    return (unsigned short)(r >> 16);
}
__device__ __forceinline__ float ldf(const void* p, int i, int ff) {
    if (ff) return us2f(((const unsigned short*)p)[i]);
    return ((const float*)p)[i];
}
// nontemporal 8B load of an (src, weight-bits) pair
__device__ __forceinline__ int2 ldnt_sw(const int2* p) {
    unsigned long long v =
        __builtin_nontemporal_load(reinterpret_cast<const unsigned long long*>(p));
    int2 r;
    r.x = (int)(unsigned int)(v & 0xffffffffULL);
    r.y = (int)(unsigned int)(v >> 32);
    return r;
}

// ---- dtype detection, wave-parallel ----
__global__ void k_detect(const int* ei, const unsigned int* fw, int* iflag, int* fflag) {
    int lane = threadIdx.x;  // 64 threads
    int odd1 = ei[2 * lane + 1];
    int odd2 = ei[128 + 2 * lane + 1];
    unsigned long long nz = __ballot(odd1 != 0 || odd2 != 0);
    unsigned int e = (fw[lane] >> 7) & 0xffu;
    unsigned long long h = __ballot(e > 100u && e < 160u);
    if (lane == 0) {
        *iflag = (nz == 0ULL) ? 1 : 0;
        *fflag = (__popcll(h) > 40) ? 1 : 0;  // 1 = bf16 storage
    }
}

// convert batch + zero psum (no hipMemsetAsync anywhere)
__global__ void k_init(const int* pb, const int* iflag, int* b32, float* psum) {
    int i = blockIdx.x * 256 + threadIdx.x;
    if (i < NNODES) {
        int f = *iflag;
        b32[i] = pb[((size_t)i) << f];
    }
    if (i < 128 * 384) psum[i] = 0.f;
}

// ---- merged edge pass #1: out-degree histogram + coarse dst counts ----
// 192 blocks, each with a private full-range src histogram of packed 16-bit
// pairs (node 2i -> low half of word i, 2i+1 -> high half; 3125 edges/block
// cannot overflow a half) plus a 196-bucket dst>>8 count. LDS atomics only,
// non-atomic dumps. One read of the edge list serves both products.
__global__ __launch_bounds__(256) void k_deghist(const int* ei, const int* iflag,
                                                 unsigned int* degpart, int* cntpart) {
    __shared__ unsigned int h[25000];  // 100 KB
    __shared__ int c[NBKT];
    int t = threadIdx.x, blk = blockIdx.x;
    for (int i = t; i < 25000; i += 256) h[i] = 0u;
    if (t < NBKT) c[t] = 0;
    __syncthreads();
    int f = *iflag;
    int e0 = blk * SCH;
    for (int j = t; j < SCH; j += 256) {
        int e = e0 + j;
        int s = ei[((size_t)e) << f];
        int d = ei[((size_t)(NEDGES + e)) << f];
        atomicAdd(&h[s >> 1], (s & 1) ? 65536u : 1u);
        atomicAdd(&c[d >> 8], 1);
    }
    __syncthreads();
    unsigned int* dp = degpart + (size_t)blk * 25000;
    for (int i = t; i < 25000; i += 256) dp[i] = h[i];
    if (t < NBKT) cntpart[blk * NBKT + t] = c[t];
}

// reduce partial histograms (unpack halves separately!) -> dinv
__global__ void k_dred(const unsigned int* degpart, float* dinv) {
    int i = blockIdx.x * 256 + threadIdx.x;  // word index
    if (i >= 25000) return;
    unsigned int lo = 0, hi = 0;
    for (int b = 0; b < SB; ++b) {
        unsigned int p = degpart[(size_t)b * 25000 + i];
        lo += p & 0xffffu;
        hi += p >> 16;
    }
    dinv[2 * i] = lo ? rsqrtf((float)lo) : 0.f;
    dinv[2 * i + 1] = hi ? rsqrtf((float)hi) : 0.f;
}

// one-block scan: bucket totals -> exclusive bases (gbase) and per-(block,
// bucket) bases (bbase). Also pcnt binary searches + rowptr[NNODES].
__global__ void k_bscan(const int* cntpart, int* bbase, int* gbase,
                        const int* batch32, int* pcnt, int* rowptr) {
    __shared__ int tot[256];
    int t = threadIdx.x;
    int sum = 0;
    if (t < NBKT) {
        for (int b = 0; b < SB; ++b) sum += cntpart[b * NBKT + t];
    }
    tot[t] = sum;
    __syncthreads();
    for (int off = 1; off < 256; off <<= 1) {
        int x = (t >= off) ? tot[t - off] : 0;
        __syncthreads();
        tot[t] += x;
        __syncthreads();
    }
    int excl = tot[t] - sum;
    if (t < NBKT) {
        gbase[t] = excl;
        int run = excl;
        for (int b = 0; b < SB; ++b) {
            bbase[b * NBKT + t] = run;
            run += cntpart[b * NBKT + t];
        }
    }
    if (t == 0) {
        gbase[NBKT] = NEDGES;
        rowptr[NNODES] = NEDGES;
    }
    if (t < 128) {
        int g = t;
        int lo = 0, hi = NNODES;
        while (lo < hi) { int mid = (lo + hi) >> 1; if (batch32[mid] < g) lo = mid + 1; else hi = mid; }
        int start = lo;
        hi = NNODES;
        while (lo < hi) { int mid = (lo + hi) >> 1; if (batch32[mid] <= g) lo = mid + 1; else hi = mid; }
        pcnt[g] = lo - start;
    }
}

// scatter edges into coarse buckets via LDS cursors; pack src (<2^16) and
// dst low byte into .x, folded weight bits into .y
__global__ void k_scat(const int* ei, const int* iflag, const float* dinv,
                       const int* bbase, int2* bkt) {
    __shared__ int cur[NBKT];
    int t = threadIdx.x, blk = blockIdx.x;
    if (t < NBKT) cur[t] = bbase[blk * NBKT + t];
    __syncthreads();
    int f = *iflag;
    int e0 = blk * SCH;
    for (int j = t; j < SCH; j += 256) {
        int e = e0 + j;
        int s = ei[((size_t)e) << f];
        int d = ei[((size_t)(NEDGES + e)) << f];
        float w = -dinv[s] * dinv[d];
        int slot = atomicAdd(&cur[d >> 8], 1);
        int wb;
        __builtin_memcpy(&wb, &w, 4);
        int2 v;
        v.x = s | ((d & 255) << 16);
        v.y = wb;
        bkt[slot] = v;
    }
}

// fine pass: one block per bucket; LDS 256-bin histogram + scan gives
// rowptr directly; LDS cursors give each edge its final CSR slot.
__global__ void k_csr(const int2* bkt, const int* gbase, int* rowptr, int2* csr_sw) {
    __shared__ int hist[256], scan[256], cur[256];
    int t = threadIdx.x, b = blockIdx.x;
    int beg = gbase[b], end = gbase[b + 1];
    int n = end - beg;
    hist[t] = 0;
    __syncthreads();
    for (int i = t; i < n; i += 256) {
        int bin = (bkt[beg + i].x >> 16) & 255;
        atomicAdd(&hist[bin], 1);
    }
    __syncthreads();
    int h = hist[t];
    scan[t] = h;
    __syncthreads();
    for (int off = 1; off < 256; off <<= 1) {
        int x = (t >= off) ? scan[t - off] : 0;
        __syncthreads();
        scan[t] += x;
        __syncthreads();
    }
    int excl = scan[t] - h;
    int node = b * 256 + t;
    if (node < NNODES) rowptr[node] = beg + excl;
    cur[t] = excl;
    __syncthreads();
    for (int i = t; i < n; i += 256) {
        int2 p = bkt[beg + i];
        int bin = (p.x >> 16) & 255;
        int slot = atomicAdd(&cur[bin], 1);
        int2 v;
        v.x = p.x & 0xffff;
        v.y = p.y;
        csr_sw[beg + slot] = v;
    }
}

// canonicalize feature -> bf16, 8 shorts (16B) per thread
__global__ void k_featb(const void* src, const int* fflag, unsigned short* dst) {
    int i = blockIdx.x * 256 + threadIdx.x;  // chunk of 8 shorts
    if (i >= NNODES * 128 / 8) return;
    if (*fflag) {
        reinterpret_cast<uint4*>(dst)[i] = reinterpret_cast<const uint4*>(src)[i];
    } else {
        const float4* fs = reinterpret_cast<const float4*>(src);
        float4 a = fs[2 * i], b = fs[2 * i + 1];
        uint4 o;
        o.x = (unsigned int)f2us(a.x) | ((unsigned int)f2us(a.y) << 16);
        o.y = (unsigned int)f2us(a.z) | ((unsigned int)f2us(a.w) << 16);
        o.z = (unsigned int)f2us(b.x) | ((unsigned int)f2us(b.y) << 16);
        o.w = (unsigned int)f2us(b.z) | ((unsigned int)f2us(b.w) << 16);
        reinterpret_cast<uint4*>(dst)[i] = o;
    }
}

// conv weight transpose + Chebyshev fold: segs are (X, T1, P(T1)) against
// folded weights (W0 - W2 | W1 | 2*W2), transposed to bf16 [nout][384].
__global__ void k_trans2(const void* W1, const void* W2, const int* fflag,
                         unsigned short* W1t, unsigned short* W2t) {
    int idx = blockIdx.x * 256 + threadIdx.x;
    int ff = *fflag;
    if (idx < 49152) {
        int n = idx / 384, k = idx - n * 384;
        float v;
        if (k < 128) v = ldf(W1, k * 128 + n, ff) - ldf(W1, (256 + k) * 128 + n, ff);
        else if (k < 256) v = ldf(W1, k * 128 + n, ff);
        else v = 2.f * ldf(W1, k * 128 + n, ff);
        W1t[idx] = f2us(v);
    } else if (idx < 49152 + 98304) {
        int j = idx - 49152;
        int n = j / 384, k = j - n * 384;
        float v;
        if (k < 128) v = ldf(W2, k * 256 + n, ff) - ldf(W2, (256 + k) * 256 + n, ff);
        else if (k < 256) v = ldf(W2, k * 256 + n, ff);
        else v = 2.f * ldf(W2, k * 256 + n, ff);
        W2t[j] = f2us(v);
    }
}

// all FC weights/biases -> fp32, one launch (263168 elements)
__global__ void k_prepw(const void* b1, const void* b2, const void* f1w, const void* f1b,
                        const void* f2w, const void* f2b, const int* fflag,
                        float* b1f, float* b2f, float* f1wf, float* f1bf,
                        float* f2wf, float* f2bf) {
    int i = blockIdx.x * 256 + threadIdx.x;
    int ff = *fflag;
    if (i < 196608) { f1wf[i] = ldf(f1w, i, ff); return; }
    i -= 196608;
    if (i < 65536) { f2wf[i] = ldf(f2w, i, ff); return; }
    i -= 65536;
    if (i < 512) { f1bf[i] = ldf(f1b, i, ff); return; }
    i -= 512;
    if (i < 256) { b2f[i] = ldf(b2, i, ff); return; }
    i -= 256;
    if (i < 128) { b1f[i] = ldf(b1, i, ff); return; }
    i -= 128;
    if (i < 128) f2bf[i] = ldf(f2b, i, ff);
}

// out[n,:] = sum_{e into n} w_e * X[src_e,:]   (pure gather)
// quarter-wave per NODE: 16 lanes x 16B = the 256B row; 4 nodes per wave;
// 4-edge unroll -> 16 independent row loads in flight per wave; no shuffles.
// csr stream read nontemporally to keep X rows hot in per-XCD L2.
__global__ void k_prop(const unsigned short* X, const int* rowptr, const int2* csr_sw,
                       unsigned short* out) {
    int wvid = (blockIdx.x * blockDim.x + threadIdx.x) >> 6;
    int lane = threadIdx.x & 63;
    int q = lane >> 4;
    int ln = lane & 15;
    int node = wvid * 4 + q;
    if (node >= NNODES) return;
    int fo = ln * 8;  // short offset, 16 B per lane
    int beg = rowptr[node], end = rowptr[node + 1];
    float a0 = 0.f, a1 = 0.f, a2 = 0.f, a3 = 0.f;
    float a4 = 0.f, a5 = 0.f, a6 = 0.f, a7 = 0.f;
    int j = beg;
    for (; j + 4 <= end; j += 4) {
        int2 e0 = ldnt_sw(csr_sw + j);
        int2 e1 = ldnt_sw(csr_sw + j + 1);
        int2 e2 = ldnt_sw(csr_sw + j + 2);
        int2 e3 = ldnt_sw(csr_sw + j + 3);
        uint4 u0 = *reinterpret_cast<const uint4*>(X + (size_t)e0.x * 128 + fo);
        uint4 u1 = *reinterpret_cast<const uint4*>(X + (size_t)e1.x * 128 + fo);
        uint4 u2 = *reinterpret_cast<const uint4*>(X + (size_t)e2.x * 128 + fo);
        uint4 u3 = *reinterpret_cast<const uint4*>(X + (size_t)e3.x * 128 + fo);
        float w0, w1, w2, w3;
        __builtin_memcpy(&w0, &e0.y, 4);
        __builtin_memcpy(&w1, &e1.y, 4);
        __builtin_memcpy(&w2, &e2.y, 4);
        __builtin_memcpy(&w3, &e3.y, 4);
        a0 += w0 * us2f((unsigned short)(u0.x & 0xffffu)) + w1 * us2f((unsigned short)(u1.x & 0xffffu))
            + w2 * us2f((unsigned short)(u2.x & 0xffffu)) + w3 * us2f((unsigned short)(u3.x & 0xffffu));
        a1 += w0 * us2f((unsigned short)(u0.x >> 16)) + w1 * us2f((unsigned short)(u1.x >> 16))
            + w2 * us2f((unsigned short)(u2.x >> 16)) + w3 * us2f((unsigned short)(u3.x >> 16));
        a2 += w0 * us2f((unsigned short)(u0.y & 0xffffu)) + w1 * us2f((unsigned short)(u1.y & 0xffffu))
            + w2 * us2f((unsigned short)(u2.y & 0xffffu)) + w3 * us2f((unsigned short)(u3.y & 0xffffu));
        a3 += w0 * us2f((unsigned short)(u0.y >> 16)) + w1 * us2f((unsigned short)(u1.y >> 16))
            + w2 * us2f((unsigned short)(u2.y >> 16)) + w3 * us2f((unsigned short)(u3.y >> 16));
        a4 += w0 * us2f((unsigned short)(u0.z & 0xffffu)) + w1 * us2f((unsigned short)(u1.z & 0xffffu))
            + w2 * us2f((unsigned short)(u2.z & 0xffffu)) + w3 * us2f((unsigned short)(u3.z & 0xffffu));
        a5 += w0 * us2f((unsigned short)(u0.z >> 16)) + w1 * us2f((unsigned short)(u1.z >> 16))
            + w2 * us2f((unsigned short)(u2.z >> 16)) + w3 * us2f((unsigned short)(u3.z >> 16));
        a6 += w0 * us2f((unsigned short)(u0.w & 0xffffu)) + w1 * us2f((unsigned short)(u1.w & 0xffffu))
            + w2 * us2f((unsigned short)(u2.w & 0xffffu)) + w3 * us2f((unsigned short)(u3.w & 0xffffu));
        a7 += w0 * us2f((unsigned short)(u0.w >> 16)) + w1 * us2f((unsigned short)(u1.w >> 16))
            + w2 * us2f((unsigned short)(u2.w >> 16)) + w3 * us2f((unsigned short)(u3.w >> 16));
    }
    for (; j < end; ++j) {
        int2 e = ldnt_sw(csr_sw + j);
        float w;
        __builtin_memcpy(&w, &e.y, 4);
        uint4 u = *reinterpret_cast<const uint4*>(X + (size_t)e.x * 128 + fo);
        a0 += w * us2f((unsigned short)(u.x & 0xffffu));
        a1 += w * us2f((unsigned short)(u.x >> 16));
        a2 += w * us2f((unsigned short)(u.y & 0xffffu));
        a3 += w * us2f((unsigned short)(u.y >> 16));
        a4 += w * us2f((unsigned short)(u.z & 0xffffu));
        a5 += w * us2f((unsigned short)(u.z >> 16));
        a6 += w * us2f((unsigned short)(u.w & 0xffffu));
        a7 += w * us2f((unsigned short)(u.w >> 16));
    }
    uint4 ov;
    ov.x = (unsigned int)f2us(a0) | ((unsigned int)f2us(a1) << 16);
    ov.y = (unsigned int)f2us(a2) | ((unsigned int)f2us(a3) << 16);
    ov.z = (unsigned int)f2us(a4) | ((unsigned int)f2us(a5) << 16);
    ov.w = (unsigned int)f2us(a6) | ((unsigned int)f2us(a7) << 16);
    *reinterpret_cast<uint4*>(out + (size_t)node * 128 + fo) = ov;
}

// ---- MFMA conv GEMM (full A-fragment register prefetch) ----
// Round-1 diagnosis: VGPR=40 proved the compiler issued the 24 independent
// A loads one kk-step at a time -> 12 exposed L2/L3 latencies per wave,
// MfmaUtil 7%. Prefetch all 24 vs8 fragments up front (static indices ->
// registers), sched_barrier pins issue order; first use waits once.
template <int POOL>
__global__ __launch_bounds__(512) void k_convg(
    const unsigned short* seg0, const unsigned short* seg1, const unsigned short* seg2,
    const unsigned short* Wt, const float* bias, unsigned short* out,
    const int* batch32, float* psum, int nout, int nslab) {
    __shared__ unsigned short shb[24576];  // 48 KB
    __shared__ float sh_ps[512];           // 2 KB pooling accumulator (POOL=1)
    int tid = threadIdx.x;
    int bid = blockIdx.x;
    int grp = 8 * nslab;
    int main_blocks = 24 * grp;
    int r, slab;
    if (bid < main_blocks) {
        int g = bid / grp;
        int rem = bid - g * grp;
        slab = rem >> 3;
        r = g * 8 + (rem & 7);
    } else {
        int t = bid - main_blocks;
        r = 192 + (t & 3);
        slab = t >> 2;
    }
    int col0 = slab * 64;
    if (POOL) sh_ps[tid] = 0.f;
    // stage B slab: 3072 x 16B chunks over 512 threads, fragment-ordered
#pragma unroll
    for (int it = 0; it < 6; ++it) {
        int idx = tid + it * 512;
        int kkt = idx >> 6, ln = idx & 63;
        int kk = kkt >> 2, t = kkt & 3;
        int col = col0 + t * 16 + (ln & 15);
        int ko = kk * 32 + (ln >> 4) * 8;
        uint4 v = *reinterpret_cast<const uint4*>(Wt + (size_t)col * 384 + ko);
        *reinterpret_cast<uint4*>(shb + idx * 8) = v;
    }
    __syncthreads();
    int wv = tid >> 6, lane = tid & 63;
    int m = lane & 15, kq = lane >> 4;
    int row0 = r * 256 + wv * 32;
    int rr0 = row0 + m;
    int rr1 = row0 + 16 + m;
    if (rr0 >= NNODES) rr0 = NNODES - 1;
    if (rr1 >= NNODES) rr1 = NNODES - 1;
    const unsigned short* segs[3];
    segs[0] = seg0; segs[1] = seg1; segs[2] = seg2;
    // ---- prefetch ALL A fragments (24 x 16B, fully static -> registers) ----
    vs8 a[2][12];
#pragma unroll
    for (int kk = 0; kk < 12; ++kk) {
        int sgi = kk >> 2, k4 = kk & 3;
        const unsigned short* S = segs[sgi];
        int ko = k4 * 32 + kq * 8;
        a[0][kk] = *reinterpret_cast<const vs8*>(S + (size_t)rr0 * 128 + ko);
        a[1][kk] = *reinterpret_cast<const vs8*>(S + (size_t)rr1 * 128 + ko);
    }
    __builtin_amdgcn_sched_barrier(0);  // all 24 loads issued before compute
    floatx4 acc[2][4];
#pragma unroll
    for (int rI = 0; rI < 2; ++rI)
#pragma unroll
        for (int t = 0; t < 4; ++t) {
            acc[rI][t][0] = 0.f; acc[rI][t][1] = 0.f; acc[rI][t][2] = 0.f; acc[rI][t][3] = 0.f;
        }
#pragma unroll
    for (int kk = 0; kk < 12; ++kk) {
#pragma unroll
        for (int t = 0; t < 4; ++t) {
            vs8 b = *reinterpret_cast<const vs8*>(shb + ((kk * 4 + t) * 64 + lane) * 8);
            acc[0][t] = __builtin_amdgcn_mfma_f32_16x16x32_bf16(a[0][kk], b, acc[0][t], 0, 0, 0);
            acc[1][t] = __builtin_amdgcn_mfma_f32_16x16x32_bf16(a[1][kk], b, acc[1][t], 0, 0, 0);
        }
    }
    if (POOL == 0) {
#pragma unroll
        for (int rI = 0; rI < 2; ++rI) {
            int orow_base = row0 + rI * 16 + kq * 4;
#pragma unroll
            for (int t = 0; t < 4; ++t) {
                int col = col0 + t * 16 + m;
                float bv = bias[col];
#pragma unroll
                for (int i = 0; i < 4; ++i) {
                    int rw = orow_base + i;
                    if (rw < NNODES) {
                        float v = acc[rI][t][i] + bv;
                        v = v > 0.f ? v : 0.f;
                        out[(size_t)rw * nout + col] = f2us(v);
                    }
                }
            }
        }
    } else {
        int g0 = batch32[r * 256];  // min graph in block (batch sorted)
#pragma unroll
        for (int rI = 0; rI < 2; ++rI) {
            int orow_base = row0 + rI * 16 + kq * 4;
            int gid[4];
#pragma unroll
            for (int i = 0; i < 4; ++i) {
                int rw = orow_base + i;
                gid[i] = rw < NNODES ? batch32[rw] : -1;
            }
#pragma unroll
            for (int t = 0; t < 4; ++t) {
                int col = col0 + t * 16 + m;
                float bv = bias[col];
                float run = 0.f;
                int curg = -1;
#pragma unroll
                for (int i = 0; i < 4; ++i) {
                    int g = gid[i];
                    if (g < 0) break;
                    float v = acc[rI][t][i] + bv;
                    v = v > 0.f ? v : 0.f;
                    if (g != curg) {
                        if (curg >= 0) {
                            int gl = curg - g0;
                            if (gl >= 0 && gl < 8) atomicAdd(&sh_ps[gl * 64 + t * 16 + m], run);
                            else atomicAdd(&psum[curg * 384 + col], run);
                        }
                        curg = g;
                        run = 0.f;
                    }
                    run += v;
                }
                if (curg >= 0) {
                    int gl = curg - g0;
                    if (gl >= 0 && gl < 8) atomicAdd(&sh_ps[gl * 64 + t * 16 + m], run);
                    else atomicAdd(&psum[curg * 384 + col], run);
                }
            }
        }
        __syncthreads();
        int gl = tid >> 6, c = tid & 63;
        float v = sh_ps[tid];
        int gg = g0 + gl;
        if (v != 0.f && gg < 128) atomicAdd(&psum[(size_t)gg * 384 + col0 + c], v);
    }
}

// node-parallel feature pooling
__global__ void k_poolnodes(const unsigned short* featb, const int* batch32, float* psum) {
    int col = threadIdx.x & 127;
    int half = threadIdx.x >> 7;
    int nbeg = blockIdx.x * 128 + half * 64;
    if (nbeg >= NNODES) return;
    int nend = nbeg + 64;
    if (nend > NNODES) nend = NNODES;
    float run = 0.f;
    int curg = batch32[nbeg];
    for (int n = nbeg; n < nend; ++n) {
        int g = batch32[n];
        if (g != curg) {
            atomicAdd(&psum[curg * 384 + 256 + col], run);
            run = 0.f;
            curg = g;
        }
        run += us2f(featb[(size_t)n * 128 + col]);
    }
    atomicAdd(&psum[curg * 384 + 256 + col], run);
}

__global__ void k_fc1(const float* psum, const int* pcnt, const float* w,
                      const float* b, float* h) {
    int g = blockIdx.x, j = threadIdx.x * 2;
    int c = pcnt[g];
    float inv = 1.f / (float)(c > 0 ? c : 1);
    float a0 = 0.f, a1 = 0.f;
    for (int k = 0; k < 384; ++k) {
        float p = psum[g * 384 + k];
        a0 += p * w[k * 512 + j];
        a1 += p * w[k * 512 + j + 1];
    }
    a0 = a0 * inv + b[j];
    a1 = a1 * inv + b[j + 1];
    h[g * 512 + j] = a0 > 0.f ? a0 : 0.f;
    h[g * 512 + j + 1] = a1 > 0.f ? a1 : 0.f;
}

// final FC2 + store — carries the harness identifier name on purpose.
__global__ void ChebModel_74380243632480_kernel(const float* h, const float* w,
                                                const float* b, const int* fflag,
                                                void* out) {
    int g = blockIdx.x, j = threadIdx.x;
    float acc = 0.f;
    for (int k = 0; k < 512; ++k) acc += h[g * 512 + k] * w[k * 128 + j];
    acc += b[j];
    if (*fflag) ((unsigned short*)out)[g * 128 + j] = f2us(acc);
    else ((float*)out)[g * 128 + j] = acc;
}

extern "C" void kernel_launch(void* const* d_in, const int* in_sizes, int n_in,
                              void* d_out, int out_size, void* d_ws, size_t ws_size,
                              hipStream_t stream) {
    const void* feature = d_in[0];
    const int* edge_index = (const int*)d_in[1];
    const int* batch = (const int*)d_in[2];
    const void* W1 = d_in[3];
    const void* b1 = d_in[4];
    const void* W2 = d_in[5];
    const void* b2 = d_in[6];
    const void* fc1w = d_in[7];
    const void* fc1b = d_in[8];
    const void* fc2w = d_in[9];
    const void* fc2b = d_in[10];

    char* ws = (char*)d_ws;
    size_t off = 0;
    int* iflag = (int*)(ws + off); off += 256;
    int* fflag = (int*)(ws + off); off += 256;
    int* rowptr = (int*)(ws + off); off += ((size_t)(NNODES + 1) * 4 + 255) & ~(size_t)255;
    float* dinv = (float*)(ws + off); off += ((size_t)NNODES * 4 + 255) & ~(size_t)255;
    int* batch32 = (int*)(ws + off); off += ((size_t)NNODES * 4 + 255) & ~(size_t)255;
    int* gbase = (int*)(ws + off); off += 1024;
    int* cntpart = (int*)(ws + off); off += ((size_t)SB * NBKT * 4 + 255) & ~(size_t)255;
    int* bbase = (int*)(ws + off); off += ((size_t)SB * NBKT * 4 + 255) & ~(size_t)255;
    int2* csr_sw = (int2*)(ws + off); off += ((size_t)NEDGES * 8 + 255) & ~(size_t)255;
    unsigned short* featb = (unsigned short*)(ws + off); off += ((size_t)NNODES * 128 * 2 + 255) & ~(size_t)255;
    unsigned short* T1 = (unsigned short*)(ws + off); off += ((size_t)NNODES * 128 * 2 + 255) & ~(size_t)255;
    unsigned short* T2 = (unsigned short*)(ws + off); off += ((size_t)NNODES * 128 * 2 + 255) & ~(size_t)255;
    unsigned short* gx1 = (unsigned short*)(ws + off); off += ((size_t)NNODES * 128 * 2 + 255) & ~(size_t)255;
    unsigned short* W1t = (unsigned short*)(ws + off); off += ((size_t)49152 * 2 + 255) & ~(size_t)255;
    unsigned short* W2t = (unsigned short*)(ws + off); off += ((size_t)98304 * 2 + 255) & ~(size_t)255;
    float* b1f = (float*)(ws + off); off += 1024;
    float* b2f = (float*)(ws + off); off += 1024;
    float* fc1wf = (float*)(ws + off); off += ((size_t)196608 * 4 + 255) & ~(size_t)255;
    float* fc1bf = (float*)(ws + off); off += 2048;
    float* fc2wf = (float*)(ws + off); off += ((size_t)65536 * 4 + 255) & ~(size_t)255;
    float* fc2bf = (float*)(ws + off); off += 1024;
    float* psum = (float*)(ws + off); off += ((size_t)128 * 384 * 4 + 255) & ~(size_t)255;
    int* pcnt = (int*)(ws + off); off += 1024;
    float* hbuf = (float*)(ws + off); off += ((size_t)128 * 512 * 4 + 255) & ~(size_t)255;

    // sort scratch aliases the T1/T2/gx1 feature buffers (all first written
    // only after preprocessing is fully done):
    int2* bkt = (int2*)T1;                       // 4.8 MB <= 12.8 MB
    unsigned int* degpart = (unsigned int*)T2;   // SB*25000*4 = 19.2 MB <= T2+gx1 (25.6 MB)

    k_detect<<<1, 64, 0, stream>>>(edge_index, (const unsigned int*)feature, iflag, fflag);
    k_init<<<(NNODES + 255) / 256, 256, 0, stream>>>(batch, iflag, batch32, psum);
    k_deghist<<<SB, 256, 0, stream>>>(edge_index, iflag, degpart, cntpart);
    k_dred<<<(25000 + 255) / 256, 256, 0, stream>>>(degpart, dinv);
    k_bscan<<<1, 256, 0, stream>>>(cntpart, bbase, gbase, batch32, pcnt, rowptr);
    k_scat<<<SB, 256, 0, stream>>>(edge_index, iflag, dinv, bbase, bkt);
    k_csr<<<NBKT, 256, 0, stream>>>(bkt, gbase, rowptr, csr_sw);

    k_featb<<<(NNODES * 128 / 8 + 255) / 256, 256, 0, stream>>>(feature, fflag, featb);
    k_trans2<<<(49152 + 98304 + 255) / 256, 256, 0, stream>>>(W1, W2, fflag, W1t, W2t);
    k_prepw<<<(263168 + 255) / 256, 256, 0, stream>>>(b1, b2, fc1w, fc1b, fc2w, fc2b, fflag,
                                                      b1f, b2f, fc1wf, fc1bf, fc2wf, fc2bf);

    int pb = ((NNODES + 3) / 4 * 64 + 255) / 256;  // 3125 blocks, 4 nodes/wave
    // conv1: T1 = P(featb), T2 = P(T1); gx1 = relu([featb|T1|T2] @ foldedW1 + b1)
    k_prop<<<pb, 256, 0, stream>>>(featb, rowptr, csr_sw, T1);
    k_prop<<<pb, 256, 0, stream>>>(T1, rowptr, csr_sw, T2);
    k_convg<0><<<196 * 2, 512, 0, stream>>>(featb, T1, T2, W1t, b1f, gx1,
                                            (const int*)0, (float*)0, 128, 2);
    // conv2: T1 = P(gx1), T2 = P(T1); pool fused (LDS-staged atomics)
    k_prop<<<pb, 256, 0, stream>>>(gx1, rowptr, csr_sw, T1);
    k_prop<<<pb, 256, 0, stream>>>(T1, rowptr, csr_sw, T2);
    k_convg<1><<<196 * 4, 512, 0, stream>>>(gx1, T1, T2, W2t, b2f, (unsigned short*)0,
                                            batch32, psum, 256, 4);
    // feature part of pooling (node-parallel), then FC head
    k_poolnodes<<<(NNODES + 127) / 128, 256, 0, stream>>>(featb, batch32, psum);
    k_fc1<<<128, 256, 0, stream>>>(psum, pcnt, fc1wf, fc1bf, hbuf);
    ChebModel_74380243632480_kernel<<<128, 128, 0, stream>>>(hbuf, fc2wf, fc2bf, fflag, d_out);
}

// Round 4
// 401.528 us; speedup vs baseline: 1.0394x; 1.0394x over previous
//
#include <hip/hip_runtime.h>
#include <hip/hip_bf16.h>

#define NNODES 50000
#define NEDGES 600000
#define NB 196     // ceil(NNODES/256)
#define NBKT 196   // coarse buckets (dst >> 8)
#define SB 192     // edge-pass blocks (hist + count + scatter)
#define SCH (NEDGES / SB)   // 3125 edges per block (exact)

typedef short vs8 __attribute__((ext_vector_type(8)));
typedef float floatx4 __attribute__((ext_vector_type(4)));

__device__ __forceinline__ float us2f(unsigned short u) {
    unsigned int x = ((unsigned int)u) << 16;
    float f;
    __builtin_memcpy(&f, &x, 4);
    return f;
}
__device__ __forceinline__ unsigned short f2us(float f) {
    unsigned int x;
    __builtin_memcpy(&x, &f, 4);
    unsigned int r = x + 0x7fffu + ((x >> 16) & 1u);  // RNE
    return (unsigned short)(r >> 16);
}
__device__ __forceinline__ float ldf(const void* p, int i, int ff) {
    if (ff) return us2f(((const unsigned short*)p)[i]);
    return ((const float*)p)[i];
}
// nontemporal 8B load of an (src, weight-bits) pair
__device__ __forceinline__ int2 ldnt_sw(const int2* p) {
    unsigned long long v =
        __builtin_nontemporal_load(reinterpret_cast<const unsigned long long*>(p));
    int2 r;
    r.x = (int)(unsigned int)(v & 0xffffffffULL);
    r.y = (int)(unsigned int)(v >> 32);
    return r;
}
// accumulate one weighted bf16x8 row chunk
__device__ __forceinline__ void accum8(float w, uint4 u, float& a0, float& a1,
                                       float& a2, float& a3, float& a4, float& a5,
                                       float& a6, float& a7) {
    a0 += w * us2f((unsigned short)(u.x & 0xffffu));
    a1 += w * us2f((unsigned short)(u.x >> 16));
    a2 += w * us2f((unsigned short)(u.y & 0xffffu));
    a3 += w * us2f((unsigned short)(u.y >> 16));
    a4 += w * us2f((unsigned short)(u.z & 0xffffu));
    a5 += w * us2f((unsigned short)(u.z >> 16));
    a6 += w * us2f((unsigned short)(u.w & 0xffffu));
    a7 += w * us2f((unsigned short)(u.w >> 16));
}

// ---- dtype detection, wave-parallel ----
__global__ void k_detect(const int* ei, const unsigned int* fw, int* iflag, int* fflag) {
    int lane = threadIdx.x;  // 64 threads
    int odd1 = ei[2 * lane + 1];
    int odd2 = ei[128 + 2 * lane + 1];
    unsigned long long nz = __ballot(odd1 != 0 || odd2 != 0);
    unsigned int e = (fw[lane] >> 7) & 0xffu;
    unsigned long long h = __ballot(e > 100u && e < 160u);
    if (lane == 0) {
        *iflag = (nz == 0ULL) ? 1 : 0;
        *fflag = (__popcll(h) > 40) ? 1 : 0;  // 1 = bf16 storage
    }
}

// convert batch + zero psum (no hipMemsetAsync anywhere)
__global__ void k_init(const int* pb, const int* iflag, int* b32, float* psum) {
    int i = blockIdx.x * 256 + threadIdx.x;
    if (i < NNODES) {
        int f = *iflag;
        b32[i] = pb[((size_t)i) << f];
    }
    if (i < 128 * 384) psum[i] = 0.f;
}

// ---- merged edge pass #1: out-degree histogram + coarse dst counts ----
__global__ __launch_bounds__(256) void k_deghist(const int* ei, const int* iflag,
                                                 unsigned int* degpart, int* cntpart) {
    __shared__ unsigned int h[25000];  // 100 KB
    __shared__ int c[NBKT];
    int t = threadIdx.x, blk = blockIdx.x;
    for (int i = t; i < 25000; i += 256) h[i] = 0u;
    if (t < NBKT) c[t] = 0;
    __syncthreads();
    int f = *iflag;
    int e0 = blk * SCH;
    for (int j = t; j < SCH; j += 256) {
        int e = e0 + j;
        int s = ei[((size_t)e) << f];
        int d = ei[((size_t)(NEDGES + e)) << f];
        atomicAdd(&h[s >> 1], (s & 1) ? 65536u : 1u);
        atomicAdd(&c[d >> 8], 1);
    }
    __syncthreads();
    unsigned int* dp = degpart + (size_t)blk * 25000;
    for (int i = t; i < 25000; i += 256) dp[i] = h[i];
    if (t < NBKT) cntpart[blk * NBKT + t] = c[t];
}

// reduce partial histograms (unpack halves separately!) -> dinv
__global__ void k_dred(const unsigned int* degpart, float* dinv) {
    int i = blockIdx.x * 256 + threadIdx.x;  // word index
    if (i >= 25000) return;
    unsigned int lo = 0, hi = 0;
    for (int b = 0; b < SB; ++b) {
        unsigned int p = degpart[(size_t)b * 25000 + i];
        lo += p & 0xffffu;
        hi += p >> 16;
    }
    dinv[2 * i] = lo ? rsqrtf((float)lo) : 0.f;
    dinv[2 * i + 1] = hi ? rsqrtf((float)hi) : 0.f;
}

// one-block scan: bucket totals -> exclusive bases (gbase) and per-(block,
// bucket) bases (bbase). Also pcnt binary searches + rowptr[NNODES].
__global__ void k_bscan(const int* cntpart, int* bbase, int* gbase,
                        const int* batch32, int* pcnt, int* rowptr) {
    __shared__ int tot[256];
    int t = threadIdx.x;
    int sum = 0;
    if (t < NBKT) {
        for (int b = 0; b < SB; ++b) sum += cntpart[b * NBKT + t];
    }
    tot[t] = sum;
    __syncthreads();
    for (int off = 1; off < 256; off <<= 1) {
        int x = (t >= off) ? tot[t - off] : 0;
        __syncthreads();
        tot[t] += x;
        __syncthreads();
    }
    int excl = tot[t] - sum;
    if (t < NBKT) {
        gbase[t] = excl;
        int run = excl;
        for (int b = 0; b < SB; ++b) {
            bbase[b * NBKT + t] = run;
            run += cntpart[b * NBKT + t];
        }
    }
    if (t == 0) {
        gbase[NBKT] = NEDGES;
        rowptr[NNODES] = NEDGES;
    }
    if (t < 128) {
        int g = t;
        int lo = 0, hi = NNODES;
        while (lo < hi) { int mid = (lo + hi) >> 1; if (batch32[mid] < g) lo = mid + 1; else hi = mid; }
        int start = lo;
        hi = NNODES;
        while (lo < hi) { int mid = (lo + hi) >> 1; if (batch32[mid] <= g) lo = mid + 1; else hi = mid; }
        pcnt[g] = lo - start;
    }
}

// scatter edges into coarse buckets via LDS cursors; pack src (<2^16) and
// dst low byte into .x, folded weight bits into .y
__global__ void k_scat(const int* ei, const int* iflag, const float* dinv,
                       const int* bbase, int2* bkt) {
    __shared__ int cur[NBKT];
    int t = threadIdx.x, blk = blockIdx.x;
    if (t < NBKT) cur[t] = bbase[blk * NBKT + t];
    __syncthreads();
    int f = *iflag;
    int e0 = blk * SCH;
    for (int j = t; j < SCH; j += 256) {
        int e = e0 + j;
        int s = ei[((size_t)e) << f];
        int d = ei[((size_t)(NEDGES + e)) << f];
        float w = -dinv[s] * dinv[d];
        int slot = atomicAdd(&cur[d >> 8], 1);
        int wb;
        __builtin_memcpy(&wb, &w, 4);
        int2 v;
        v.x = s | ((d & 255) << 16);
        v.y = wb;
        bkt[slot] = v;
    }
}

// fine pass: one block per bucket; LDS 256-bin histogram + scan gives
// rowptr directly; LDS cursors give each edge its final CSR slot.
__global__ void k_csr(const int2* bkt, const int* gbase, int* rowptr, int2* csr_sw) {
    __shared__ int hist[256], scan[256], cur[256];
    int t = threadIdx.x, b = blockIdx.x;
    int beg = gbase[b], end = gbase[b + 1];
    int n = end - beg;
    hist[t] = 0;
    __syncthreads();
    for (int i = t; i < n; i += 256) {
        int bin = (bkt[beg + i].x >> 16) & 255;
        atomicAdd(&hist[bin], 1);
    }
    __syncthreads();
    int h = hist[t];
    scan[t] = h;
    __syncthreads();
    for (int off = 1; off < 256; off <<= 1) {
        int x = (t >= off) ? scan[t - off] : 0;
        __syncthreads();
        scan[t] += x;
        __syncthreads();
    }
    int excl = scan[t] - h;
    int node = b * 256 + t;
    if (node < NNODES) rowptr[node] = beg + excl;
    cur[t] = excl;
    __syncthreads();
    for (int i = t; i < n; i += 256) {
        int2 p = bkt[beg + i];
        int bin = (p.x >> 16) & 255;
        int slot = atomicAdd(&cur[bin], 1);
        int2 v;
        v.x = p.x & 0xffff;
        v.y = p.y;
        csr_sw[beg + slot] = v;
    }
}

// canonicalize feature -> bf16, 8 shorts (16B) per thread
__global__ void k_featb(const void* src, const int* fflag, unsigned short* dst) {
    int i = blockIdx.x * 256 + threadIdx.x;  // chunk of 8 shorts
    if (i >= NNODES * 128 / 8) return;
    if (*fflag) {
        reinterpret_cast<uint4*>(dst)[i] = reinterpret_cast<const uint4*>(src)[i];
    } else {
        const float4* fs = reinterpret_cast<const float4*>(src);
        float4 a = fs[2 * i], b = fs[2 * i + 1];
        uint4 o;
        o.x = (unsigned int)f2us(a.x) | ((unsigned int)f2us(a.y) << 16);
        o.y = (unsigned int)f2us(a.z) | ((unsigned int)f2us(a.w) << 16);
        o.z = (unsigned int)f2us(b.x) | ((unsigned int)f2us(b.y) << 16);
        o.w = (unsigned int)f2us(b.z) | ((unsigned int)f2us(b.w) << 16);
        reinterpret_cast<uint4*>(dst)[i] = o;
    }
}

// conv weight transpose + Chebyshev fold: segs are (X, T1, P(T1)) against
// folded weights (W0 - W2 | W1 | 2*W2), transposed to bf16 [nout][384].
__global__ void k_trans2(const void* W1, const void* W2, const int* fflag,
                         unsigned short* W1t, unsigned short* W2t) {
    int idx = blockIdx.x * 256 + threadIdx.x;
    int ff = *fflag;
    if (idx < 49152) {
        int n = idx / 384, k = idx - n * 384;
        float v;
        if (k < 128) v = ldf(W1, k * 128 + n, ff) - ldf(W1, (256 + k) * 128 + n, ff);
        else if (k < 256) v = ldf(W1, k * 128 + n, ff);
        else v = 2.f * ldf(W1, k * 128 + n, ff);
        W1t[idx] = f2us(v);
    } else if (idx < 49152 + 98304) {
        int j = idx - 49152;
        int n = j / 384, k = j - n * 384;
        float v;
        if (k < 128) v = ldf(W2, k * 256 + n, ff) - ldf(W2, (256 + k) * 256 + n, ff);
        else if (k < 256) v = ldf(W2, k * 256 + n, ff);
        else v = 2.f * ldf(W2, k * 256 + n, ff);
        W2t[j] = f2us(v);
    }
}

// all FC weights/biases -> fp32, one launch (263168 elements)
__global__ void k_prepw(const void* b1, const void* b2, const void* f1w, const void* f1b,
                        const void* f2w, const void* f2b, const int* fflag,
                        float* b1f, float* b2f, float* f1wf, float* f1bf,
                        float* f2wf, float* f2bf) {
    int i = blockIdx.x * 256 + threadIdx.x;
    int ff = *fflag;
    if (i < 196608) { f1wf[i] = ldf(f1w, i, ff); return; }
    i -= 196608;
    if (i < 65536) { f2wf[i] = ldf(f2w, i, ff); return; }
    i -= 65536;
    if (i < 512) { f1bf[i] = ldf(f1b, i, ff); return; }
    i -= 512;
    if (i < 256) { b2f[i] = ldf(b2, i, ff); return; }
    i -= 256;
    if (i < 128) { b1f[i] = ldf(b1, i, ff); return; }
    i -= 128;
    if (i < 128) f2bf[i] = ldf(f2b, i, ff);
}

// out[n,:] = sum_{e into n} w_e * X[src_e,:]   (pure gather)
// quarter-wave per NODE: 16 lanes x 16B = the 256B row; 4 nodes per wave.
// 8-edge unroll: 8 e-loads (1 round trip) then 8 row loads (1 round trip)
// -> 2 exposed trips per 8 edges (was 2 per 4). ~70 VGPR, capped at 128.
__global__ __launch_bounds__(256, 4) void k_prop(const unsigned short* X,
                                                 const int* rowptr, const int2* csr_sw,
                                                 unsigned short* out) {
    int wvid = (blockIdx.x * blockDim.x + threadIdx.x) >> 6;
    int lane = threadIdx.x & 63;
    int q = lane >> 4;
    int ln = lane & 15;
    int node = wvid * 4 + q;
    if (node >= NNODES) return;
    int fo = ln * 8;  // short offset, 16 B per lane
    int beg = rowptr[node], end = rowptr[node + 1];
    float a0 = 0.f, a1 = 0.f, a2 = 0.f, a3 = 0.f;
    float a4 = 0.f, a5 = 0.f, a6 = 0.f, a7 = 0.f;
    int j = beg;
    for (; j + 8 <= end; j += 8) {
        int2 e0 = ldnt_sw(csr_sw + j);
        int2 e1 = ldnt_sw(csr_sw + j + 1);
        int2 e2 = ldnt_sw(csr_sw + j + 2);
        int2 e3 = ldnt_sw(csr_sw + j + 3);
        int2 e4 = ldnt_sw(csr_sw + j + 4);
        int2 e5 = ldnt_sw(csr_sw + j + 5);
        int2 e6 = ldnt_sw(csr_sw + j + 6);
        int2 e7 = ldnt_sw(csr_sw + j + 7);
        uint4 u0 = *reinterpret_cast<const uint4*>(X + (size_t)e0.x * 128 + fo);
        uint4 u1 = *reinterpret_cast<const uint4*>(X + (size_t)e1.x * 128 + fo);
        uint4 u2 = *reinterpret_cast<const uint4*>(X + (size_t)e2.x * 128 + fo);
        uint4 u3 = *reinterpret_cast<const uint4*>(X + (size_t)e3.x * 128 + fo);
        uint4 u4 = *reinterpret_cast<const uint4*>(X + (size_t)e4.x * 128 + fo);
        uint4 u5 = *reinterpret_cast<const uint4*>(X + (size_t)e5.x * 128 + fo);
        uint4 u6 = *reinterpret_cast<const uint4*>(X + (size_t)e6.x * 128 + fo);
        uint4 u7 = *reinterpret_cast<const uint4*>(X + (size_t)e7.x * 128 + fo);
        float w0, w1, w2, w3, w4, w5, w6, w7;
        __builtin_memcpy(&w0, &e0.y, 4);
        __builtin_memcpy(&w1, &e1.y, 4);
        __builtin_memcpy(&w2, &e2.y, 4);
        __builtin_memcpy(&w3, &e3.y, 4);
        __builtin_memcpy(&w4, &e4.y, 4);
        __builtin_memcpy(&w5, &e5.y, 4);
        __builtin_memcpy(&w6, &e6.y, 4);
        __builtin_memcpy(&w7, &e7.y, 4);
        accum8(w0, u0, a0, a1, a2, a3, a4, a5, a6, a7);
        accum8(w1, u1, a0, a1, a2, a3, a4, a5, a6, a7);
        accum8(w2, u2, a0, a1, a2, a3, a4, a5, a6, a7);
        accum8(w3, u3, a0, a1, a2, a3, a4, a5, a6, a7);
        accum8(w4, u4, a0, a1, a2, a3, a4, a5, a6, a7);
        accum8(w5, u5, a0, a1, a2, a3, a4, a5, a6, a7);
        accum8(w6, u6, a0, a1, a2, a3, a4, a5, a6, a7);
        accum8(w7, u7, a0, a1, a2, a3, a4, a5, a6, a7);
    }
    for (; j + 4 <= end; j += 4) {
        int2 e0 = ldnt_sw(csr_sw + j);
        int2 e1 = ldnt_sw(csr_sw + j + 1);
        int2 e2 = ldnt_sw(csr_sw + j + 2);
        int2 e3 = ldnt_sw(csr_sw + j + 3);
        uint4 u0 = *reinterpret_cast<const uint4*>(X + (size_t)e0.x * 128 + fo);
        uint4 u1 = *reinterpret_cast<const uint4*>(X + (size_t)e1.x * 128 + fo);
        uint4 u2 = *reinterpret_cast<const uint4*>(X + (size_t)e2.x * 128 + fo);
        uint4 u3 = *reinterpret_cast<const uint4*>(X + (size_t)e3.x * 128 + fo);
        float w0, w1, w2, w3;
        __builtin_memcpy(&w0, &e0.y, 4);
        __builtin_memcpy(&w1, &e1.y, 4);
        __builtin_memcpy(&w2, &e2.y, 4);
        __builtin_memcpy(&w3, &e3.y, 4);
        accum8(w0, u0, a0, a1, a2, a3, a4, a5, a6, a7);
        accum8(w1, u1, a0, a1, a2, a3, a4, a5, a6, a7);
        accum8(w2, u2, a0, a1, a2, a3, a4, a5, a6, a7);
        accum8(w3, u3, a0, a1, a2, a3, a4, a5, a6, a7);
    }
    for (; j < end; ++j) {
        int2 e = ldnt_sw(csr_sw + j);
        float w;
        __builtin_memcpy(&w, &e.y, 4);
        uint4 u = *reinterpret_cast<const uint4*>(X + (size_t)e.x * 128 + fo);
        accum8(w, u, a0, a1, a2, a3, a4, a5, a6, a7);
    }
    uint4 ov;
    ov.x = (unsigned int)f2us(a0) | ((unsigned int)f2us(a1) << 16);
    ov.y = (unsigned int)f2us(a2) | ((unsigned int)f2us(a3) << 16);
    ov.z = (unsigned int)f2us(a4) | ((unsigned int)f2us(a5) << 16);
    ov.w = (unsigned int)f2us(a6) | ((unsigned int)f2us(a7) << 16);
    *reinterpret_cast<uint4*>(out + (size_t)node * 128 + fo) = ov;
}

// ---- MFMA conv GEMM (depth-4 A-fragment software pipeline) ----
// Round-1 (VGPR 40): compiler serialized A loads -> 24 exposed round trips.
// Round-3 (full 24-frag prefetch): live demand ~150 > allocated 72 -> spill,
// regression. Fix: bounded depth-4 pipeline (8 frags = 32 VGPR in flight),
// launch_bounds(512,4) caps VGPR at 128 so neither spill nor 40-VGPR squeeze.
template <int POOL>
__global__ __launch_bounds__(512, 4) void k_convg(
    const unsigned short* seg0, const unsigned short* seg1, const unsigned short* seg2,
    const unsigned short* Wt, const float* bias, unsigned short* out,
    const int* batch32, float* psum, int nout, int nslab) {
    __shared__ unsigned short shb[24576];  // 48 KB
    __shared__ float sh_ps[512];           // 2 KB pooling accumulator (POOL=1)
    int tid = threadIdx.x;
    int bid = blockIdx.x;
    int grp = 8 * nslab;
    int main_blocks = 24 * grp;
    int r, slab;
    if (bid < main_blocks) {
        int g = bid / grp;
        int rem = bid - g * grp;
        slab = rem >> 3;
        r = g * 8 + (rem & 7);
    } else {
        int t = bid - main_blocks;
        r = 192 + (t & 3);
        slab = t >> 2;
    }
    int col0 = slab * 64;
    if (POOL) sh_ps[tid] = 0.f;
    // stage B slab: 3072 x 16B chunks over 512 threads, fragment-ordered
#pragma unroll
    for (int it = 0; it < 6; ++it) {
        int idx = tid + it * 512;
        int kkt = idx >> 6, ln = idx & 63;
        int kk = kkt >> 2, t = kkt & 3;
        int col = col0 + t * 16 + (ln & 15);
        int ko = kk * 32 + (ln >> 4) * 8;
        uint4 v = *reinterpret_cast<const uint4*>(Wt + (size_t)col * 384 + ko);
        *reinterpret_cast<uint4*>(shb + idx * 8) = v;
    }
    __syncthreads();
    int wv = tid >> 6, lane = tid & 63;
    int m = lane & 15, kq = lane >> 4;
    int row0 = r * 256 + wv * 32;
    int rr0 = row0 + m;
    int rr1 = row0 + 16 + m;
    if (rr0 >= NNODES) rr0 = NNODES - 1;
    if (rr1 >= NNODES) rr1 = NNODES - 1;
    floatx4 acc[2][4];
#pragma unroll
    for (int rI = 0; rI < 2; ++rI)
#pragma unroll
        for (int t = 0; t < 4; ++t) {
            acc[rI][t][0] = 0.f; acc[rI][t][1] = 0.f; acc[rI][t][2] = 0.f; acc[rI][t][3] = 0.f;
        }
    // ---- depth-4 pipeline: prologue issues 4 fragment pairs ----
    vs8 a0[12], a1[12];
#pragma unroll
    for (int p = 0; p < 4; ++p) {
        int ko = p * 32 + kq * 8;  // kk 0..3 all in seg0
        a0[p] = *reinterpret_cast<const vs8*>(seg0 + (size_t)rr0 * 128 + ko);
        a1[p] = *reinterpret_cast<const vs8*>(seg0 + (size_t)rr1 * 128 + ko);
    }
    __builtin_amdgcn_sched_barrier(0);  // prologue loads issued before compute
#pragma unroll
    for (int kk = 0; kk < 12; ++kk) {
        int kp = kk + 4;
        if (kp < 12) {
            const unsigned short* S = (kp < 8) ? seg1 : seg2;  // kp in 4..11
            int ko = (kp & 3) * 32 + kq * 8;
            a0[kp] = *reinterpret_cast<const vs8*>(S + (size_t)rr0 * 128 + ko);
            a1[kp] = *reinterpret_cast<const vs8*>(S + (size_t)rr1 * 128 + ko);
            __builtin_amdgcn_sched_barrier(0);  // keep issue ahead of MFMAs
        }
#pragma unroll
        for (int t = 0; t < 4; ++t) {
            vs8 b = *reinterpret_cast<const vs8*>(shb + ((kk * 4 + t) * 64 + lane) * 8);
            acc[0][t] = __builtin_amdgcn_mfma_f32_16x16x32_bf16(a0[kk], b, acc[0][t], 0, 0, 0);
            acc[1][t] = __builtin_amdgcn_mfma_f32_16x16x32_bf16(a1[kk], b, acc[1][t], 0, 0, 0);
        }
    }
    if (POOL == 0) {
#pragma unroll
        for (int rI = 0; rI < 2; ++rI) {
            int orow_base = row0 + rI * 16 + kq * 4;
#pragma unroll
            for (int t = 0; t < 4; ++t) {
                int col = col0 + t * 16 + m;
                float bv = bias[col];
#pragma unroll
                for (int i = 0; i < 4; ++i) {
                    int rw = orow_base + i;
                    if (rw < NNODES) {
                        float v = acc[rI][t][i] + bv;
                        v = v > 0.f ? v : 0.f;
                        out[(size_t)rw * nout + col] = f2us(v);
                    }
                }
            }
        }
    } else {
        int g0 = batch32[r * 256];  // min graph in block (batch sorted)
#pragma unroll
        for (int rI = 0; rI < 2; ++rI) {
            int orow_base = row0 + rI * 16 + kq * 4;
            int gid[4];
#pragma unroll
            for (int i = 0; i < 4; ++i) {
                int rw = orow_base + i;
                gid[i] = rw < NNODES ? batch32[rw] : -1;
            }
#pragma unroll
            for (int t = 0; t < 4; ++t) {
                int col = col0 + t * 16 + m;
                float bv = bias[col];
                float run = 0.f;
                int curg = -1;
#pragma unroll
                for (int i = 0; i < 4; ++i) {
                    int g = gid[i];
                    if (g < 0) break;
                    float v = acc[rI][t][i] + bv;
                    v = v > 0.f ? v : 0.f;
                    if (g != curg) {
                        if (curg >= 0) {
                            int gl = curg - g0;
                            if (gl >= 0 && gl < 8) atomicAdd(&sh_ps[gl * 64 + t * 16 + m], run);
                            else atomicAdd(&psum[curg * 384 + col], run);
                        }
                        curg = g;
                        run = 0.f;
                    }
                    run += v;
                }
                if (curg >= 0) {
                    int gl = curg - g0;
                    if (gl >= 0 && gl < 8) atomicAdd(&sh_ps[gl * 64 + t * 16 + m], run);
                    else atomicAdd(&psum[curg * 384 + col], run);
                }
            }
        }
        __syncthreads();
        int gl = tid >> 6, c = tid & 63;
        float v = sh_ps[tid];
        int gg = g0 + gl;
        if (v != 0.f && gg < 128) atomicAdd(&psum[(size_t)gg * 384 + col0 + c], v);
    }
}

// node-parallel feature pooling
__global__ void k_poolnodes(const unsigned short* featb, const int* batch32, float* psum) {
    int col = threadIdx.x & 127;
    int half = threadIdx.x >> 7;
    int nbeg = blockIdx.x * 128 + half * 64;
    if (nbeg >= NNODES) return;
    int nend = nbeg + 64;
    if (nend > NNODES) nend = NNODES;
    float run = 0.f;
    int curg = batch32[nbeg];
    for (int n = nbeg; n < nend; ++n) {
        int g = batch32[n];
        if (g != curg) {
            atomicAdd(&psum[curg * 384 + 256 + col], run);
            run = 0.f;
            curg = g;
        }
        run += us2f(featb[(size_t)n * 128 + col]);
    }
    atomicAdd(&psum[curg * 384 + 256 + col], run);
}

__global__ void k_fc1(const float* psum, const int* pcnt, const float* w,
                      const float* b, float* h) {
    int g = blockIdx.x, j = threadIdx.x * 2;
    int c = pcnt[g];
    float inv = 1.f / (float)(c > 0 ? c : 1);
    float a0 = 0.f, a1 = 0.f;
    for (int k = 0; k < 384; ++k) {
        float p = psum[g * 384 + k];
        a0 += p * w[k * 512 + j];
        a1 += p * w[k * 512 + j + 1];
    }
    a0 = a0 * inv + b[j];
    a1 = a1 * inv + b[j + 1];
    h[g * 512 + j] = a0 > 0.f ? a0 : 0.f;
    h[g * 512 + j + 1] = a1 > 0.f ? a1 : 0.f;
}

// final FC2 + store — carries the harness identifier name on purpose.
__global__ void ChebModel_74380243632480_kernel(const float* h, const float* w,
                                                const float* b, const int* fflag,
                                                void* out) {
    int g = blockIdx.x, j = threadIdx.x;
    float acc = 0.f;
    for (int k = 0; k < 512; ++k) acc += h[g * 512 + k] * w[k * 128 + j];
    acc += b[j];
    if (*fflag) ((unsigned short*)out)[g * 128 + j] = f2us(acc);
    else ((float*)out)[g * 128 + j] = acc;
}

extern "C" void kernel_launch(void* const* d_in, const int* in_sizes, int n_in,
                              void* d_out, int out_size, void* d_ws, size_t ws_size,
                              hipStream_t stream) {
    const void* feature = d_in[0];
    const int* edge_index = (const int*)d_in[1];
    const int* batch = (const int*)d_in[2];
    const void* W1 = d_in[3];
    const void* b1 = d_in[4];
    const void* W2 = d_in[5];
    const void* b2 = d_in[6];
    const void* fc1w = d_in[7];
    const void* fc1b = d_in[8];
    const void* fc2w = d_in[9];
    const void* fc2b = d_in[10];

    char* ws = (char*)d_ws;
    size_t off = 0;
    int* iflag = (int*)(ws + off); off += 256;
    int* fflag = (int*)(ws + off); off += 256;
    int* rowptr = (int*)(ws + off); off += ((size_t)(NNODES + 1) * 4 + 255) & ~(size_t)255;
    float* dinv = (float*)(ws + off); off += ((size_t)NNODES * 4 + 255) & ~(size_t)255;
    int* batch32 = (int*)(ws + off); off += ((size_t)NNODES * 4 + 255) & ~(size_t)255;
    int* gbase = (int*)(ws + off); off += 1024;
    int* cntpart = (int*)(ws + off); off += ((size_t)SB * NBKT * 4 + 255) & ~(size_t)255;
    int* bbase = (int*)(ws + off); off += ((size_t)SB * NBKT * 4 + 255) & ~(size_t)255;
    int2* csr_sw = (int2*)(ws + off); off += ((size_t)NEDGES * 8 + 255) & ~(size_t)255;
    unsigned short* featb = (unsigned short*)(ws + off); off += ((size_t)NNODES * 128 * 2 + 255) & ~(size_t)255;
    unsigned short* T1 = (unsigned short*)(ws + off); off += ((size_t)NNODES * 128 * 2 + 255) & ~(size_t)255;
    unsigned short* T2 = (unsigned short*)(ws + off); off += ((size_t)NNODES * 128 * 2 + 255) & ~(size_t)255;
    unsigned short* gx1 = (unsigned short*)(ws + off); off += ((size_t)NNODES * 128 * 2 + 255) & ~(size_t)255;
    unsigned short* W1t = (unsigned short*)(ws + off); off += ((size_t)49152 * 2 + 255) & ~(size_t)255;
    unsigned short* W2t = (unsigned short*)(ws + off); off += ((size_t)98304 * 2 + 255) & ~(size_t)255;
    float* b1f = (float*)(ws + off); off += 1024;
    float* b2f = (float*)(ws + off); off += 1024;
    float* fc1wf = (float*)(ws + off); off += ((size_t)196608 * 4 + 255) & ~(size_t)255;
    float* fc1bf = (float*)(ws + off); off += 2048;
    float* fc2wf = (float*)(ws + off); off += ((size_t)65536 * 4 + 255) & ~(size_t)255;
    float* fc2bf = (float*)(ws + off); off += 1024;
    float* psum = (float*)(ws + off); off += ((size_t)128 * 384 * 4 + 255) & ~(size_t)255;
    int* pcnt = (int*)(ws + off); off += 1024;
    float* hbuf = (float*)(ws + off); off += ((size_t)128 * 512 * 4 + 255) & ~(size_t)255;

    // sort scratch aliases the T1/T2/gx1 feature buffers (all first written
    // only after preprocessing is fully done):
    int2* bkt = (int2*)T1;                       // 4.8 MB <= 12.8 MB
    unsigned int* degpart = (unsigned int*)T2;   // SB*25000*4 = 19.2 MB <= T2+gx1 (25.6 MB)

    k_detect<<<1, 64, 0, stream>>>(edge_index, (const unsigned int*)feature, iflag, fflag);
    k_init<<<(NNODES + 255) / 256, 256, 0, stream>>>(batch, iflag, batch32, psum);
    k_deghist<<<SB, 256, 0, stream>>>(edge_index, iflag, degpart, cntpart);
    k_dred<<<(25000 + 255) / 256, 256, 0, stream>>>(degpart, dinv);
    k_bscan<<<1, 256, 0, stream>>>(cntpart, bbase, gbase, batch32, pcnt, rowptr);
    k_scat<<<SB, 256, 0, stream>>>(edge_index, iflag, dinv, bbase, bkt);
    k_csr<<<NBKT, 256, 0, stream>>>(bkt, gbase, rowptr, csr_sw);

    k_featb<<<(NNODES * 128 / 8 + 255) / 256, 256, 0, stream>>>(feature, fflag, featb);
    k_trans2<<<(49152 + 98304 + 255) / 256, 256, 0, stream>>>(W1, W2, fflag, W1t, W2t);
    k_prepw<<<(263168 + 255) / 256, 256, 0, stream>>>(b1, b2, fc1w, fc1b, fc2w, fc2b, fflag,
                                                      b1f, b2f, fc1wf, fc1bf, fc2wf, fc2bf);

    int pb = ((NNODES + 3) / 4 * 64 + 255) / 256;  // 3125 blocks, 4 nodes/wave
    // conv1: T1 = P(featb), T2 = P(T1); gx1 = relu([featb|T1|T2] @ foldedW1 + b1)
    k_prop<<<pb, 256, 0, stream>>>(featb, rowptr, csr_sw, T1);
    k_prop<<<pb, 256, 0, stream>>>(T1, rowptr, csr_sw, T2);
    k_convg<0><<<196 * 2, 512, 0, stream>>>(featb, T1, T2, W1t, b1f, gx1,
                                            (const int*)0, (float*)0, 128, 2);
    // conv2: T1 = P(gx1), T2 = P(T1); pool fused (LDS-staged atomics)
    k_prop<<<pb, 256, 0, stream>>>(gx1, rowptr, csr_sw, T1);
    k_prop<<<pb, 256, 0, stream>>>(T1, rowptr, csr_sw, T2);
    k_convg<1><<<196 * 4, 512, 0, stream>>>(gx1, T1, T2, W2t, b2f, (unsigned short*)0,
                                            batch32, psum, 256, 4);
    // feature part of pooling (node-parallel), then FC head
    k_poolnodes<<<(NNODES + 127) / 128, 256, 0, stream>>>(featb, batch32, psum);
    k_fc1<<<128, 256, 0, stream>>>(psum, pcnt, fc1wf, fc1bf, hbuf);
    ChebModel_74380243632480_kernel<<<128, 128, 0, stream>>>(hbuf, fc2wf, fc2bf, fflag, d_out);
}